// Round 16
// baseline (127.782 us; speedup 1.0000x reference)
//
#include <hip/hip_runtime.h>

#define NN    4096      // nodes
#define DD    256       // feature dim (= H*HID)
#define NH    4         // heads
#define HIDD  64        // per-head hidden
#define NE    131072    // edges
#define WPR   (NN/32)   // 128 u32 words per adjacency bitmask row
#define SLOPE 0.2f
#define CAP   128       // max degree; Binom(131072,1/4096) max over 4096 rows ~56 incl self
#define LDBH  130       // Bs leading dim (shorts): conflict-free frag ds_read_b128

typedef __attribute__((ext_vector_type(8))) short short8;   // 8 bf16 in 4 VGPRs
typedef __attribute__((ext_vector_type(4))) float f32x4;

__device__ __forceinline__ unsigned short f2bf(float x) {   // RNE, matches HW cvt
    unsigned u = __float_as_uint(x);
    u += 0x7fffu + ((u >> 16) & 1u);
    return (unsigned short)(u >> 16);
}
__device__ __forceinline__ float bf2f(unsigned short v) {
    return __uint_as_float((unsigned)v << 16);
}

// ---------------------------------------------------------------- K1: MFMA GEMM + adj-zero/self + fused e1/e2  (R14, unchanged)
// + resets the k23 barrier counter (node boundary orders it) -> stateless.
__global__ __launch_bounds__(256, 4) void k1_mfma_gemm(
    const float* __restrict__ in, const float* __restrict__ W,
    const float* __restrict__ att, unsigned short* __restrict__ Whb,
    float* __restrict__ e1, float* __restrict__ e2,
    unsigned int* __restrict__ adj, int* __restrict__ ctr) {
    int b = blockIdx.x;
    int t = threadIdx.x;
    int lane = t & 63, wv = t >> 6;
    int rt = b >> 2, head = b & 3;
    int row0 = rt * 16;
    int col0 = head * 64;

    if (b == 0 && t == 0)
        __hip_atomic_store(ctr, 0, __ATOMIC_RELAXED, __HIP_MEMORY_SCOPE_AGENT);

    __shared__ unsigned short Bs[64][LDBH];    // one K=128 half, reused
    __shared__ float s1[4][16], s2[4][16];

    // ---- issue ALL B loads first (16 float4, both halves) for MLP
    int c4 = (t & 15) * 4;
    int kk = t >> 4;
    float4 b0[8], b1[8];
    #pragma unroll
    for (int i = 0; i < 8; ++i) {
        int kl = i * 16 + kk;
        b0[i] = *(const float4*)(W + kl * DD + col0 + c4);
        b1[i] = *(const float4*)(W + (128 + kl) * DD + col0 + c4);
    }

    // adj zero + self bits (head-0 blocks own rows [16rt,+16) = 512 uint4)
    if (head == 0) {
        uint4* adj4 = (uint4*)adj;
        #pragma unroll
        for (int q = 0; q < 2; ++q) {
            int g = rt * 512 + q * 256 + t;
            int r = g >> 5;
            int sw = r * WPR + (r >> 5);
            uint4 z{0u, 0u, 0u, 0u};
            if ((sw >> 2) == g) ((unsigned*)&z)[sw & 3] = 1u << (r & 31);
            adj4[g] = z;
        }
    }

    const float* Arow = in + (row0 + (lane & 15)) * DD;
    int kb = (lane >> 4) * 8;
    const unsigned short* Bp = &Bs[wv * 16 + (lane & 15)][0];
    f32x4 acc = {0.f, 0.f, 0.f, 0.f};

    #pragma unroll
    for (int p = 0; p < 2; ++p) {
        if (p) __syncthreads();                // phase-0 frag reads done
        #pragma unroll
        for (int i = 0; i < 8; ++i) {
            int kl = i * 16 + kk;
            float4 w = p ? b1[i] : b0[i];
            Bs[c4 + 0][kl] = f2bf(w.x);
            Bs[c4 + 1][kl] = f2bf(w.y);
            Bs[c4 + 2][kl] = f2bf(w.z);
            Bs[c4 + 3][kl] = f2bf(w.w);
        }
        __syncthreads();
        #pragma unroll
        for (int s = 0; s < 4; ++s) {
            int k = p * 128 + s * 32 + kb;
            float4 x0 = *(const float4*)(Arow + k);
            float4 x1 = *(const float4*)(Arow + k + 4);
            short8 af, bf;
            af[0] = (short)f2bf(x0.x); af[1] = (short)f2bf(x0.y);
            af[2] = (short)f2bf(x0.z); af[3] = (short)f2bf(x0.w);
            af[4] = (short)f2bf(x1.x); af[5] = (short)f2bf(x1.y);
            af[6] = (short)f2bf(x1.z); af[7] = (short)f2bf(x1.w);
            bf = *(const short8*)(Bp + s * 32 + kb);
            acc = __builtin_amdgcn_mfma_f32_16x16x32_bf16(af, bf, acc, 0, 0, 0);
        }
    }

    // ---- store C (bf16) + e1/e2 epilogue (C/D: col=lane&15, row=(lane>>4)*4+r)
    int rg = lane >> 4, cl = lane & 15;
    int crow = row0 + rg * 4;
    int ccol = col0 + wv * 16 + cl;
    float a1w = att[wv * 16 + cl];
    float a2w = att[HIDD + wv * 16 + cl];
    float p1[4], p2[4];
    #pragma unroll
    for (int r = 0; r < 4; ++r) {
        Whb[(crow + r) * DD + ccol] = f2bf(acc[r]);
        p1[r] = acc[r] * a1w;
        p2[r] = acc[r] * a2w;
    }
    #pragma unroll
    for (int off = 1; off < 16; off <<= 1) {
        #pragma unroll
        for (int r = 0; r < 4; ++r) {
            p1[r] += __shfl_xor(p1[r], off);
            p2[r] += __shfl_xor(p2[r], off);
        }
    }
    if (cl == 0) {
        #pragma unroll
        for (int r = 0; r < 4; ++r) {
            s1[wv][rg * 4 + r] = p1[r];
            s2[wv][rg * 4 + r] = p2[r];
        }
    }
    __syncthreads();
    if (t < 16) {
        e1[(row0 + t) * NH + head] = s1[0][t] + s1[1][t] + s1[2][t] + s1[3][t];
        e2[(row0 + t) * NH + head] = s2[0][t] + s2[1][t] + s2[2][t] + s2[3][t];
    }
}

// ---------------------------------------------------------------- K23: edge bits + grid barrier + per-wave GAT
// 1024 blocks x 256 thr, __launch_bounds__(256,4): 4 blocks/CU at 10KB LDS,
// <=128 VGPR -> ALL 1024 co-resident by construction (2x margin) -> the
// arrive-and-spin barrier cannot deadlock. k1 reset ctr=0 this call.
__global__ __launch_bounds__(256, 4) void k23_gat(
    const int* __restrict__ edges, unsigned int* __restrict__ adj,
    const unsigned short* __restrict__ Whb,
    const float* __restrict__ e1, const float* __restrict__ e2,
    float* __restrict__ out, int* __restrict__ ctr) {
    int b = blockIdx.x, t = threadIdx.x;
    int lane = t & 63, wv = t >> 6;

    __shared__ int   nbr[4][CAP];
    __shared__ float wgt[4][CAP][NH];

    // ---- phase A: 128 edges/block (1024*128 == NE), dedup via idempotent OR
    if (t < 128) {
        int idx = b * 128 + t;
        int r = edges[idx * 3 + 0];
        int c = edges[idx * 3 + 1];
        atomicOr(&adj[r * WPR + (c >> 5)], 1u << (c & 31));
    }

    // ---- software grid barrier (release -> arrive -> spin -> acquire)
    __syncthreads();
    if (t == 0) {
        __threadfence();                        // release: OR visible device-wide
        __hip_atomic_fetch_add(ctr, 1, __ATOMIC_RELAXED, __HIP_MEMORY_SCOPE_AGENT);
        while (__hip_atomic_load(ctr, __ATOMIC_RELAXED, __HIP_MEMORY_SCOPE_AGENT) < 1024) {}
        __threadfence();                        // acquire: see all blocks' ORs
    }
    __syncthreads();

    // ---- phase C: wave wv -> row i; scan 2 words/lane, prefix compaction
    int i = b * 4 + wv;
    float4 e1q = *(const float4*)(e1 + i * NH);
    float  e1v[NH] = {e1q.x, e1q.y, e1q.z, e1q.w};

    unsigned w0 = __hip_atomic_load(&adj[i * WPR + lane],      __ATOMIC_RELAXED, __HIP_MEMORY_SCOPE_AGENT);
    unsigned w1 = __hip_atomic_load(&adj[i * WPR + 64 + lane], __ATOMIC_RELAXED, __HIP_MEMORY_SCOPE_AGENT);
    int pc = __popc(w0) + __popc(w1);
    int incl = pc;
    #pragma unroll
    for (int off = 1; off < 64; off <<= 1) {
        int v = __shfl_up(incl, off);
        if (lane >= off) incl += v;
    }
    int cn = __shfl(incl, 63);
    if (cn > CAP) cn = CAP;
    int d = incl - pc;                       // exclusive prefix

    float zl[NH] = {0.f, 0.f, 0.f, 0.f};
    #pragma unroll
    for (int q = 0; q < 2; ++q) {
        unsigned bits = q ? w1 : w0;
        int base = (q * 64 + lane) * 32;
        while (bits) {
            int bp = __ffs(bits) - 1;
            bits &= bits - 1;
            int j = base + bp;
            if (d < CAP) {
                nbr[wv][d] = j;
                float4 ev = *(const float4*)(e2 + j * NH);
                float e2v[NH] = {ev.x, ev.y, ev.z, ev.w};
                #pragma unroll
                for (int h = 0; h < NH; ++h) {
                    float s = e1v[h] + e2v[h];
                    s = (s >= 0.f) ? s : SLOPE * s;      // LeakyReLU
                    float w = __expf(s);
                    wgt[wv][d][h] = w;
                    zl[h] += w;
                }
            }
            ++d;
        }
    }
    #pragma unroll
    for (int off = 32; off; off >>= 1) {
        #pragma unroll
        for (int h = 0; h < NH; ++h) zl[h] += __shfl_xor(zl[h], off);
    }
    __syncthreads();                         // wave-private LDS settled (belt+braces)

    // ---- gather: lane = f, all 4 heads per lane; 128B coalesced per (d,h)
    float acc[NH] = {0.f, 0.f, 0.f, 0.f};
    for (int dd = 0; dd < cn; ++dd) {
        int j = nbr[wv][dd];
        const unsigned short* row = Whb + j * DD + lane;
        #pragma unroll
        for (int h = 0; h < NH; ++h)
            acc[h] = fmaf(wgt[wv][dd][h], bf2f(row[h * HIDD]), acc[h]);
    }
    #pragma unroll
    for (int h = 0; h < NH; ++h) {
        float r = acc[h] / zl[h];
        out[i * DD + h * HIDD + lane] = (r > 0.f) ? r : (__expf(r) - 1.f);
    }
}

// ---------------------------------------------------------------- launcher
extern "C" void kernel_launch(void* const* d_in, const int* in_sizes, int n_in,
                              void* d_out, int out_size, void* d_ws, size_t ws_size,
                              hipStream_t stream) {
    const float* inp   = (const float*)d_in[0];
    const int*   edges = (const int*)d_in[1];
    // d_in[2] = num_node (scalar, constant 4096) — unused
    const float* W     = (const float*)d_in[3];
    const float* att   = (const float*)d_in[4];
    float*       out   = (float*)d_out;

    char* ws = (char*)d_ws;
    unsigned short* Whb = (unsigned short*)(ws);                   // 2 MB
    float*        e1  = (float*)(ws + (2u << 20));                 // 64 KB
    float*        e2  = (float*)(ws + (2u << 20) + (64u << 10));   // 64 KB
    unsigned int* adj = (unsigned int*)(ws + (2u << 20) + (128u << 10)); // 2 MB
    int*          ctr = (int*)(ws + (5u << 20));                   // 4 B

    k1_mfma_gemm<<<NN / 16 * NH, 256, 0, stream>>>(inp, W, att, Whb, e1, e2, adj, ctr);
    k23_gat<<<1024, 256, 0, stream>>>(edges, adj, Whb, e1, e2, out, ctr);
}

// Round 17
// 38.127 us; speedup vs baseline: 3.3515x; 3.3515x over previous
//
#include <hip/hip_runtime.h>

#define NN    4096      // nodes
#define DD    256       // feature dim (= H*HID)
#define NH    4         // heads
#define HIDD  64        // per-head hidden
#define NE    131072    // edges
#define WPR   (NN/32)   // 128 u32 words per adjacency bitmask row
#define SLOPE 0.2f
#define CAP   128       // max degree; Binom(131072,1/4096) max over 4096 rows ~56 incl self
#define LDBH  130       // Bs leading dim (shorts): conflict-free frag ds_read_b128

typedef __attribute__((ext_vector_type(8))) short short8;   // 8 bf16 in 4 VGPRs
typedef __attribute__((ext_vector_type(4))) float f32x4;

__device__ __forceinline__ unsigned short f2bf(float x) {   // RNE, matches HW cvt
    unsigned u = __float_as_uint(x);
    u += 0x7fffu + ((u >> 16) & 1u);
    return (unsigned short)(u >> 16);
}
__device__ __forceinline__ float bf2f(unsigned short v) {
    return __uint_as_float((unsigned)v << 16);
}

// ---------------------------------------------------------------- K1: MFMA GEMM + adj-zero/self + fused e1/e2  (R14, unchanged)
__global__ __launch_bounds__(256, 4) void k1_mfma_gemm(
    const float* __restrict__ in, const float* __restrict__ W,
    const float* __restrict__ att, unsigned short* __restrict__ Whb,
    float* __restrict__ e1, float* __restrict__ e2,
    unsigned int* __restrict__ adj) {
    int b = blockIdx.x;
    int t = threadIdx.x;
    int lane = t & 63, wv = t >> 6;
    int rt = b >> 2, head = b & 3;
    int row0 = rt * 16;
    int col0 = head * 64;

    __shared__ unsigned short Bs[64][LDBH];    // one K=128 half, reused
    __shared__ float s1[4][16], s2[4][16];

    // ---- issue ALL B loads first (16 float4, both halves) for MLP
    int c4 = (t & 15) * 4;
    int kk = t >> 4;
    float4 b0[8], b1[8];
    #pragma unroll
    for (int i = 0; i < 8; ++i) {
        int kl = i * 16 + kk;
        b0[i] = *(const float4*)(W + kl * DD + col0 + c4);
        b1[i] = *(const float4*)(W + (128 + kl) * DD + col0 + c4);
    }

    // adj zero + self bits (head-0 blocks own rows [16rt,+16) = 512 uint4)
    if (head == 0) {
        uint4* adj4 = (uint4*)adj;
        #pragma unroll
        for (int q = 0; q < 2; ++q) {
            int g = rt * 512 + q * 256 + t;
            int r = g >> 5;
            int sw = r * WPR + (r >> 5);
            uint4 z{0u, 0u, 0u, 0u};
            if ((sw >> 2) == g) ((unsigned*)&z)[sw & 3] = 1u << (r & 31);
            adj4[g] = z;
        }
    }

    const float* Arow = in + (row0 + (lane & 15)) * DD;
    int kb = (lane >> 4) * 8;
    const unsigned short* Bp = &Bs[wv * 16 + (lane & 15)][0];
    f32x4 acc = {0.f, 0.f, 0.f, 0.f};

    #pragma unroll
    for (int p = 0; p < 2; ++p) {
        if (p) __syncthreads();                // phase-0 frag reads done
        #pragma unroll
        for (int i = 0; i < 8; ++i) {
            int kl = i * 16 + kk;
            float4 w = p ? b1[i] : b0[i];
            Bs[c4 + 0][kl] = f2bf(w.x);
            Bs[c4 + 1][kl] = f2bf(w.y);
            Bs[c4 + 2][kl] = f2bf(w.z);
            Bs[c4 + 3][kl] = f2bf(w.w);
        }
        __syncthreads();
        #pragma unroll
        for (int s = 0; s < 4; ++s) {
            int k = p * 128 + s * 32 + kb;
            float4 x0 = *(const float4*)(Arow + k);
            float4 x1 = *(const float4*)(Arow + k + 4);
            short8 af, bf;
            af[0] = (short)f2bf(x0.x); af[1] = (short)f2bf(x0.y);
            af[2] = (short)f2bf(x0.z); af[3] = (short)f2bf(x0.w);
            af[4] = (short)f2bf(x1.x); af[5] = (short)f2bf(x1.y);
            af[6] = (short)f2bf(x1.z); af[7] = (short)f2bf(x1.w);
            bf = *(const short8*)(Bp + s * 32 + kb);
            acc = __builtin_amdgcn_mfma_f32_16x16x32_bf16(af, bf, acc, 0, 0, 0);
        }
    }

    // ---- store C (bf16) + e1/e2 epilogue (C/D: col=lane&15, row=(lane>>4)*4+r)
    int rg = lane >> 4, cl = lane & 15;
    int crow = row0 + rg * 4;
    int ccol = col0 + wv * 16 + cl;
    float a1w = att[wv * 16 + cl];
    float a2w = att[HIDD + wv * 16 + cl];
    float p1[4], p2[4];
    #pragma unroll
    for (int r = 0; r < 4; ++r) {
        Whb[(crow + r) * DD + ccol] = f2bf(acc[r]);
        p1[r] = acc[r] * a1w;
        p2[r] = acc[r] * a2w;
    }
    #pragma unroll
    for (int off = 1; off < 16; off <<= 1) {
        #pragma unroll
        for (int r = 0; r < 4; ++r) {
            p1[r] += __shfl_xor(p1[r], off);
            p2[r] += __shfl_xor(p2[r], off);
        }
    }
    if (cl == 0) {
        #pragma unroll
        for (int r = 0; r < 4; ++r) {
            s1[wv][rg * 4 + r] = p1[r];
            s2[wv][rg * 4 + r] = p2[r];
        }
    }
    __syncthreads();
    if (t < 16) {
        e1[(row0 + t) * NH + head] = s1[0][t] + s1[1][t] + s1[2][t] + s1[3][t];
        e2[(row0 + t) * NH + head] = s2[0][t] + s2[1][t] + s2[2][t] + s2[3][t];
    }
}

// ---------------------------------------------------------------- K2: edge bits (dedup via idempotent OR)
__global__ __launch_bounds__(256) void k2_build(
    const int* __restrict__ edges, unsigned int* __restrict__ adj) {
    int t = blockIdx.x * 256 + threadIdx.x;        // grid == NE exactly
    int r = edges[t * 3 + 0];
    int c = edges[t * 3 + 1];
    atomicOr(&adj[r * WPR + (c >> 5)], 1u << (c & 31));
}

// ---------------------------------------------------------------- K3: wave-per-row GAT (1024 blocks)
// Wave wv -> row 4b+wv. Scan: 2 words/lane, pure-shuffle prefix compaction.
// Gather: lane covers features [4*lane, 4*lane+4) (head lane>>4): per
// neighbor ONE uint2 load (512B/wave burst) + float4 out store.
__global__ __launch_bounds__(256) void k3_gat(
    const unsigned int* __restrict__ adj, const unsigned short* __restrict__ Whb,
    const float* __restrict__ e1, const float* __restrict__ e2,
    float* __restrict__ out) {
    int b = blockIdx.x, t = threadIdx.x;
    int lane = t & 63, wv = t >> 6;
    int i = b * 4 + wv;

    __shared__ int   nbr[4][CAP];
    __shared__ float wgt[4][CAP][NH];

    float4 e1q = *(const float4*)(e1 + i * NH);
    float  e1v[NH] = {e1q.x, e1q.y, e1q.z, e1q.w};

    unsigned w0 = adj[i * WPR + lane];
    unsigned w1 = adj[i * WPR + 64 + lane];
    int pc = __popc(w0) + __popc(w1);
    int incl = pc;
    #pragma unroll
    for (int off = 1; off < 64; off <<= 1) {
        int v = __shfl_up(incl, off);
        if (lane >= off) incl += v;
    }
    int cn = __shfl(incl, 63);
    if (cn > CAP) cn = CAP;
    int d = incl - pc;                       // exclusive prefix

    float zl[NH] = {0.f, 0.f, 0.f, 0.f};
    #pragma unroll
    for (int q = 0; q < 2; ++q) {
        unsigned bits = q ? w1 : w0;
        int base = (q * 64 + lane) * 32;
        while (bits) {
            int bp = __ffs(bits) - 1;
            bits &= bits - 1;
            int j = base + bp;
            if (d < CAP) {
                nbr[wv][d] = j;
                float4 ev = *(const float4*)(e2 + j * NH);
                float e2v[NH] = {ev.x, ev.y, ev.z, ev.w};
                #pragma unroll
                for (int h = 0; h < NH; ++h) {
                    float s = e1v[h] + e2v[h];
                    s = (s >= 0.f) ? s : SLOPE * s;      // LeakyReLU
                    float w = __expf(s);
                    wgt[wv][d][h] = w;
                    zl[h] += w;
                }
            }
            ++d;
        }
    }
    #pragma unroll
    for (int off = 32; off; off >>= 1) {
        #pragma unroll
        for (int h = 0; h < NH; ++h) zl[h] += __shfl_xor(zl[h], off);
    }
    __syncthreads();                         // 4-wave alignment (cheap)

    // ---- gather: lane covers cols [4*lane, 4*lane+4), head h0 = lane>>4
    int h0 = lane >> 4;
    float Z = zl[h0];
    float a0 = 0.f, a1 = 0.f, a2 = 0.f, a3 = 0.f;
    const unsigned short* base = Whb + 4 * lane;
    for (int dd = 0; dd < cn; ++dd) {
        int j = nbr[wv][dd];
        float w = wgt[wv][dd][h0];           // LDS broadcast per head group
        uint2 v = *(const uint2*)(base + j * DD);
        a0 = fmaf(w, bf2f((unsigned short)(v.x & 0xffff)), a0);
        a1 = fmaf(w, bf2f((unsigned short)(v.x >> 16)),    a1);
        a2 = fmaf(w, bf2f((unsigned short)(v.y & 0xffff)), a2);
        a3 = fmaf(w, bf2f((unsigned short)(v.y >> 16)),    a3);
    }
    float4 o;
    o.x = a0 / Z; o.y = a1 / Z; o.z = a2 / Z; o.w = a3 / Z;
    o.x = (o.x > 0.f) ? o.x : (__expf(o.x) - 1.f);
    o.y = (o.y > 0.f) ? o.y : (__expf(o.y) - 1.f);
    o.z = (o.z > 0.f) ? o.z : (__expf(o.z) - 1.f);
    o.w = (o.w > 0.f) ? o.w : (__expf(o.w) - 1.f);
    *(float4*)(out + i * DD + 4 * lane) = o;
}

// ---------------------------------------------------------------- launcher
extern "C" void kernel_launch(void* const* d_in, const int* in_sizes, int n_in,
                              void* d_out, int out_size, void* d_ws, size_t ws_size,
                              hipStream_t stream) {
    const float* inp   = (const float*)d_in[0];
    const int*   edges = (const int*)d_in[1];
    // d_in[2] = num_node (scalar, constant 4096) — unused
    const float* W     = (const float*)d_in[3];
    const float* att   = (const float*)d_in[4];
    float*       out   = (float*)d_out;

    char* ws = (char*)d_ws;
    unsigned short* Whb = (unsigned short*)(ws);                   // 2 MB
    float*        e1  = (float*)(ws + (2u << 20));                 // 64 KB
    float*        e2  = (float*)(ws + (2u << 20) + (64u << 10));   // 64 KB
    unsigned int* adj = (unsigned int*)(ws + (2u << 20) + (128u << 10)); // 2 MB

    k1_mfma_gemm<<<NN / 16 * NH, 256, 0, stream>>>(inp, W, att, Whb, e1, e2, adj);
    k2_build<<<NE / 256, 256, 0, stream>>>(edges, adj);
    k3_gat<<<NN / 4, 256, 0, stream>>>(adj, Whb, e1, e2, out);
}